// Round 5
// baseline (1785.686 us; speedup 1.0000x reference)
//
#include <hip/hip_runtime.h>

// GCN encoder: h1 = relu(x@fcW+fcb); h2 = relu(gcn(h1,W1,b1)); out = relu(gcn(h2,W2,b2))
// gcn(x,W,b)[i] = sum_{e:dst=i} (x@W)[src_e]*norm_e + (x@W)[i]*dinv[i]^2 + b
// Aggregation: dst-sorted CSR built on device, per-node gather (no fp32 atomics).
// GEMM: single-wave 64x64 blocks (64 thr, 8x8/thread, BK=8, dbuf LDS) -> many
// resident independent waves; barriers are 1-wave (cheap).

namespace {
constexpr int NN = 20000;
constexpr int NE = 320000;
constexpr int IN_FT = 256, HID1 = 400, HID2 = 200, OUT_FT = 128;
}

// deg (weighted, +1 self loop) and integer count per dst in one pass
__global__ __launch_bounds__(256) void deg_count_kernel(const int* __restrict__ dst,
                                                        const float* __restrict__ ew,
                                                        float* __restrict__ deg,
                                                        int* __restrict__ cnt) {
  int tid = blockIdx.x * 256 + threadIdx.x;
  if (tid < NE) {
    int d = dst[tid];
    unsafeAtomicAdd(&deg[d], ew[tid]);
    atomicAdd(&cnt[d], 1);
  } else if (tid < NE + NN) {
    unsafeAtomicAdd(&deg[tid - NE], 1.0f);  // self-loop weight 1
  }
}

__global__ __launch_bounds__(256) void dinv_kernel(float* __restrict__ deg) {
  int i = blockIdx.x * 256 + threadIdx.x;
  if (i < NN) {
    float d = deg[i];
    deg[i] = d > 0.f ? rsqrtf(d) : 0.f;  // in place: deg -> dinv
  }
}

__global__ __launch_bounds__(256) void norm_kernel(const int* __restrict__ src,
                                                   const int* __restrict__ dst,
                                                   const float* __restrict__ ew,
                                                   const float* __restrict__ dinv,
                                                   float* __restrict__ nrm) {
  int e = blockIdx.x * 256 + threadIdx.x;
  if (e < NE) {
    nrm[e] = dinv[src[e]] * ew[e] * dinv[dst[e]];
  }
}

// single-block exclusive scan of count[NN] -> rowptr[NN+1]
__global__ __launch_bounds__(1024) void scan_kernel(const int* __restrict__ count,
                                                    int* __restrict__ rowptr) {
  constexpr int CHUNK = (NN + 1023) / 1024;  // 20
  __shared__ int partial[1024];
  const int t = threadIdx.x;
  const int base = t * CHUNK;
  int s = 0;
#pragma unroll
  for (int i = 0; i < CHUNK; ++i) {
    int idx = base + i;
    if (idx < NN) s += count[idx];
  }
  partial[t] = s;
  __syncthreads();
  for (int off = 1; off < 1024; off <<= 1) {
    int v = 0;
    if (t >= off) v = partial[t - off];
    __syncthreads();
    if (t >= off) partial[t] += v;
    __syncthreads();
  }
  int excl = partial[t] - s;
#pragma unroll
  for (int i = 0; i < CHUNK; ++i) {
    int idx = base + i;
    if (idx < NN) {
      rowptr[idx] = excl;
      excl += count[idx];
    }
  }
  if (t == 1023) rowptr[NN] = partial[1023];
}

__global__ __launch_bounds__(256) void scatter_kernel(const int* __restrict__ src,
                                                      const int* __restrict__ dst,
                                                      const float* __restrict__ nrm,
                                                      int* __restrict__ fill,
                                                      int* __restrict__ srcS,
                                                      float* __restrict__ wS) {
  int e = blockIdx.x * 256 + threadIdx.x;
  if (e >= NE) return;
  int d = dst[e];
  int pos = atomicAdd(&fill[d], 1);
  srcS[pos] = src[e];
  wS[pos] = nrm[e];
}

// C[M,Nc] = A[M,K] @ B[K,Nc] (+bias)(relu).
// One 64-lane wave per block; 64x64 tile; 8x8 per thread; BK=8; dbuf LDS.
// Requires K % 8 == 0, Nc % 4 == 0.
template <bool BIAS, bool RELU>
__global__ __launch_bounds__(64, 4) void gemm_wave_kernel(const float* __restrict__ A,
                                                          const float* __restrict__ B,
                                                          const float* __restrict__ bias,
                                                          float* __restrict__ C,
                                                          int M, int K, int Nc) {
  __shared__ float As[2][8][64];  // [buf][k][m]
  __shared__ float Bs[2][8][64];  // [buf][k][n]
  const int lane = threadIdx.x;
  const int ty = lane >> 3, tx = lane & 7;
  const int m0 = blockIdx.y * 64, n0 = blockIdx.x * 64;
  const int mA = m0 + lane;                 // A-staging: one row per lane
  const bool aok = mA < M;
  const int rB = lane >> 3;                 // B-staging: row 0..7
  const int cB = (lane & 7) * 8;            // 8 cols per lane
  const int KT = K >> 3;

  float acc[8][8];
#pragma unroll
  for (int i = 0; i < 8; ++i)
#pragma unroll
    for (int j = 0; j < 8; ++j) acc[i][j] = 0.f;

  float4 aV0, aV1, bV0, bV1;

  auto gload = [&](int k0) {
    aV0 = aV1 = bV0 = bV1 = make_float4(0.f, 0.f, 0.f, 0.f);
    if (aok) {
      const float* ap = A + (size_t)mA * K + k0;
      aV0 = *reinterpret_cast<const float4*>(ap);
      aV1 = *reinterpret_cast<const float4*>(ap + 4);
    }
    const float* bp = B + (size_t)(k0 + rB) * Nc + n0 + cB;
    if (n0 + cB < Nc) bV0 = *reinterpret_cast<const float4*>(bp);       // Nc%4==0
    if (n0 + cB + 4 < Nc) bV1 = *reinterpret_cast<const float4*>(bp + 4);
  };

  auto sstore = [&](int buf) {
    As[buf][0][lane] = aV0.x;  // 2-way bank alias (free)
    As[buf][1][lane] = aV0.y;
    As[buf][2][lane] = aV0.z;
    As[buf][3][lane] = aV0.w;
    As[buf][4][lane] = aV1.x;
    As[buf][5][lane] = aV1.y;
    As[buf][6][lane] = aV1.z;
    As[buf][7][lane] = aV1.w;
    *reinterpret_cast<float4*>(&Bs[buf][rB][cB]) = bV0;
    *reinterpret_cast<float4*>(&Bs[buf][rB][cB + 4]) = bV1;
  };

  auto comp = [&](int buf) {
#pragma unroll
    for (int kk = 0; kk < 8; ++kk) {
      float4 a0 = *reinterpret_cast<const float4*>(&As[buf][kk][ty * 8]);
      float4 a1 = *reinterpret_cast<const float4*>(&As[buf][kk][ty * 8 + 4]);
      float4 b0 = *reinterpret_cast<const float4*>(&Bs[buf][kk][tx * 8]);
      float4 b1 = *reinterpret_cast<const float4*>(&Bs[buf][kk][tx * 8 + 4]);
      const float av[8] = {a0.x, a0.y, a0.z, a0.w, a1.x, a1.y, a1.z, a1.w};
      const float bv[8] = {b0.x, b0.y, b0.z, b0.w, b1.x, b1.y, b1.z, b1.w};
#pragma unroll
      for (int i = 0; i < 8; ++i)
#pragma unroll
        for (int j = 0; j < 8; ++j) acc[i][j] = fmaf(av[i], bv[j], acc[i][j]);
    }
  };

  gload(0);
  sstore(0);
  __syncthreads();  // 1-wave barrier: cheap
  for (int kt = 0; kt < KT; ++kt) {
    const bool more = (kt + 1 < KT);
    if (more) gload((kt + 1) * 8);  // prefetch to regs, in flight under compute
    comp(kt & 1);
    __syncthreads();
    if (more) {
      sstore((kt + 1) & 1);
      __syncthreads();
    }
  }

  // epilogue: 8 rows x 8 cols per thread
  const int nc0 = n0 + tx * 8;
  float4 bb0 = make_float4(0.f, 0.f, 0.f, 0.f), bb1 = bb0;
  if (BIAS) {
    if (nc0 < Nc) bb0 = *reinterpret_cast<const float4*>(bias + nc0);
    if (nc0 + 4 < Nc) bb1 = *reinterpret_cast<const float4*>(bias + nc0 + 4);
  }
#pragma unroll
  for (int i = 0; i < 8; ++i) {
    const int m = m0 + ty * 8 + i;
    if (m >= M) continue;
    float* cp = C + (size_t)m * Nc + nc0;
    if (nc0 < Nc) {
      float4 v = make_float4(acc[i][0], acc[i][1], acc[i][2], acc[i][3]);
      if (BIAS) { v.x += bb0.x; v.y += bb0.y; v.z += bb0.z; v.w += bb0.w; }
      if (RELU) {
        v.x = fmaxf(v.x, 0.f); v.y = fmaxf(v.y, 0.f);
        v.z = fmaxf(v.z, 0.f); v.w = fmaxf(v.w, 0.f);
      }
      *reinterpret_cast<float4*>(cp) = v;
    }
    if (nc0 + 4 < Nc) {
      float4 v = make_float4(acc[i][4], acc[i][5], acc[i][6], acc[i][7]);
      if (BIAS) { v.x += bb1.x; v.y += bb1.y; v.z += bb1.z; v.w += bb1.w; }
      if (RELU) {
        v.x = fmaxf(v.x, 0.f); v.y = fmaxf(v.y, 0.f);
        v.z = fmaxf(v.z, 0.f); v.w = fmaxf(v.w, 0.f);
      }
      *reinterpret_cast<float4*>(cp + 4) = v;
    }
  }
}

// Fused gather-aggregate + self-loop + bias + relu. One 64-lane wave per node.
template <int F>
__global__ __launch_bounds__(256) void agg_gather_kernel(const int* __restrict__ rowptr,
                                                         const int* __restrict__ srcS,
                                                         const float* __restrict__ wS,
                                                         const float* __restrict__ t,
                                                         const float* __restrict__ dinv,
                                                         const float* __restrict__ bias,
                                                         float* __restrict__ out) {
  constexpr int NITER = (F + 63) / 64;
  const int wv = threadIdx.x >> 6, lane = threadIdx.x & 63;
  const int node = blockIdx.x * 4 + wv;
  if (node >= NN) return;
  const int beg = rowptr[node], end = rowptr[node + 1];
  float acc[NITER];
#pragma unroll
  for (int i = 0; i < NITER; ++i) acc[i] = 0.f;
  for (int j = beg; j < end; ++j) {
    const int s = srcS[j];
    const float wgt = wS[j];
    const float* row = t + (size_t)s * F;
#pragma unroll
    for (int i = 0; i < NITER; ++i) {
      int f = lane + i * 64;
      if (f < F) acc[i] += row[f] * wgt;
    }
  }
  const float di = dinv[node];
  const float self_w = di * di;
  const float* trow = t + (size_t)node * F;
  float* orow = out + (size_t)node * F;
#pragma unroll
  for (int i = 0; i < NITER; ++i) {
    int f = lane + i * 64;
    if (f < F) {
      float v = fmaf(trow[f], self_w, acc[i]) + bias[f];
      orow[f] = fmaxf(v, 0.f);
    }
  }
}

extern "C" void kernel_launch(void* const* d_in, const int* in_sizes, int n_in,
                              void* d_out, int out_size, void* d_ws, size_t ws_size,
                              hipStream_t stream) {
  const float* x = (const float*)d_in[0];
  const int* ei = (const int*)d_in[1];  // int32 per harness conversion
  const float* ea = (const float*)d_in[2];
  const float* fcW = (const float*)d_in[3];
  const float* fcb = (const float*)d_in[4];
  const float* W1 = (const float*)d_in[5];
  const float* b1 = (const float*)d_in[6];
  const float* W2 = (const float*)d_in[7];
  const float* b2 = (const float*)d_in[8];
  const int* srcIdx = ei;       // edge_index[0]
  const int* dstIdx = ei + NE;  // edge_index[1]

  char* ws = (char*)d_ws;
  constexpr size_t MB = 1u << 20;
  float* dinv = (float*)(ws);            // 80 KB
  float* nrm = (float*)(ws + 1 * MB);    // 1.28 MB
  int* rowptr = (int*)(ws + 3 * MB);     // 80 KB (NN+1)
  int* cnt = (int*)(ws + 4 * MB);        // 80 KB (count, then fill cursor)
  int* srcS = (int*)(ws + 5 * MB);       // 1.28 MB
  float* wS = (float*)(ws + 7 * MB);     // 1.28 MB
  float* bufA = (float*)(ws + 9 * MB);   // 32 MB: h1 [N,400] -> h2 [N,200]
  float* bufB = (float*)(ws + 41 * MB);  // 16 MB: t1 [N,200] -> t2 [N,128]
  // peak ws use: 57 MB

  // --- normalization + CSR (shared by both GCN layers) ---
  hipMemsetAsync(dinv, 0, NN * sizeof(float), stream);
  hipMemsetAsync(cnt, 0, NN * sizeof(int), stream);
  deg_count_kernel<<<(NE + NN + 255) / 256, 256, 0, stream>>>(dstIdx, ea, dinv, cnt);
  dinv_kernel<<<(NN + 255) / 256, 256, 0, stream>>>(dinv);
  norm_kernel<<<(NE + 255) / 256, 256, 0, stream>>>(srcIdx, dstIdx, ea, dinv, nrm);
  scan_kernel<<<1, 1024, 0, stream>>>(cnt, rowptr);
  hipMemcpyAsync(cnt, rowptr, NN * sizeof(int), hipMemcpyDeviceToDevice, stream);
  scatter_kernel<<<(NE + 255) / 256, 256, 0, stream>>>(srcIdx, dstIdx, nrm, cnt, srcS, wS);

  const int MB64 = (NN + 63) / 64;  // 313 row blocks

  // --- h1 = relu(x @ fcW + fcb) ---
  float* h1 = bufA;
  gemm_wave_kernel<true, true><<<dim3((HID1 + 63) / 64, MB64), 64, 0, stream>>>(
      x, fcW, fcb, h1, NN, IN_FT, HID1);

  // --- layer 1: t1 = h1 @ W1; h2 = relu(agg(t1) + t1*dinv^2 + b1) ---
  float* t1 = bufB;
  gemm_wave_kernel<false, false><<<dim3((HID2 + 63) / 64, MB64), 64, 0, stream>>>(
      h1, W1, nullptr, t1, NN, HID1, HID2);
  float* h2 = bufA;  // h1 dead after t1 GEMM
  agg_gather_kernel<HID2><<<(NN + 3) / 4, 256, 0, stream>>>(
      rowptr, srcS, wS, t1, dinv, b1, h2);

  // --- layer 2: t2 = h2 @ W2; out = relu(agg(t2) + t2*dinv^2 + b2) ---
  float* t2 = bufB;  // t1 dead after agg1
  gemm_wave_kernel<false, false><<<dim3((OUT_FT + 63) / 64, MB64), 64, 0, stream>>>(
      h2, W2, nullptr, t2, NN, HID2, OUT_FT);
  agg_gather_kernel<OUT_FT><<<(NN + 3) / 4, 256, 0, stream>>>(
      rowptr, srcS, wS, t2, dinv, b2, (float*)d_out);
}

// Round 6
// 996.732 us; speedup vs baseline: 1.7915x; 1.7915x over previous
//
#include <hip/hip_runtime.h>

// GCN encoder: h1 = relu(x@fcW+fcb); h2 = relu(gcn(h1,W1,b1)); out = relu(gcn(h2,W2,b2))
// gcn(x,W,b)[i] = sum_{e:dst=i} (x@W)[src_e]*norm_e + (x@W)[i]*dinv[i]^2 + b
// Aggregation: dst-sorted CSR built on device, per-node gather (no fp32 atomics).
// GEMM: single-wave 64x64 blocks (64 thr, 8x8/thread, BK=8, dbuf LDS).
// __launch_bounds__(64,3): cap ~170 VGPR -- (64,4) capped at 128 and the 8x8
// accumulator spilled to scratch (3.1 GB/GEMM of scratch traffic, round 5).

namespace {
constexpr int NN = 20000;
constexpr int NE = 320000;
constexpr int IN_FT = 256, HID1 = 400, HID2 = 200, OUT_FT = 128;
}

// deg (weighted, +1 self loop) and integer count per dst in one pass
__global__ __launch_bounds__(256) void deg_count_kernel(const int* __restrict__ dst,
                                                        const float* __restrict__ ew,
                                                        float* __restrict__ deg,
                                                        int* __restrict__ cnt) {
  int tid = blockIdx.x * 256 + threadIdx.x;
  if (tid < NE) {
    int d = dst[tid];
    unsafeAtomicAdd(&deg[d], ew[tid]);
    atomicAdd(&cnt[d], 1);
  } else if (tid < NE + NN) {
    unsafeAtomicAdd(&deg[tid - NE], 1.0f);  // self-loop weight 1
  }
}

__global__ __launch_bounds__(256) void dinv_kernel(float* __restrict__ deg) {
  int i = blockIdx.x * 256 + threadIdx.x;
  if (i < NN) {
    float d = deg[i];
    deg[i] = d > 0.f ? rsqrtf(d) : 0.f;  // in place: deg -> dinv
  }
}

__global__ __launch_bounds__(256) void norm_kernel(const int* __restrict__ src,
                                                   const int* __restrict__ dst,
                                                   const float* __restrict__ ew,
                                                   const float* __restrict__ dinv,
                                                   float* __restrict__ nrm) {
  int e = blockIdx.x * 256 + threadIdx.x;
  if (e < NE) {
    nrm[e] = dinv[src[e]] * ew[e] * dinv[dst[e]];
  }
}

// single-block exclusive scan of count[NN] -> rowptr[NN+1]
__global__ __launch_bounds__(1024) void scan_kernel(const int* __restrict__ count,
                                                    int* __restrict__ rowptr) {
  constexpr int CHUNK = (NN + 1023) / 1024;  // 20
  __shared__ int partial[1024];
  const int t = threadIdx.x;
  const int base = t * CHUNK;
  int s = 0;
#pragma unroll
  for (int i = 0; i < CHUNK; ++i) {
    int idx = base + i;
    if (idx < NN) s += count[idx];
  }
  partial[t] = s;
  __syncthreads();
  for (int off = 1; off < 1024; off <<= 1) {
    int v = 0;
    if (t >= off) v = partial[t - off];
    __syncthreads();
    if (t >= off) partial[t] += v;
    __syncthreads();
  }
  int excl = partial[t] - s;
#pragma unroll
  for (int i = 0; i < CHUNK; ++i) {
    int idx = base + i;
    if (idx < NN) {
      rowptr[idx] = excl;
      excl += count[idx];
    }
  }
  if (t == 1023) rowptr[NN] = partial[1023];
}

__global__ __launch_bounds__(256) void scatter_kernel(const int* __restrict__ src,
                                                      const int* __restrict__ dst,
                                                      const float* __restrict__ nrm,
                                                      int* __restrict__ fill,
                                                      int* __restrict__ srcS,
                                                      float* __restrict__ wS) {
  int e = blockIdx.x * 256 + threadIdx.x;
  if (e >= NE) return;
  int d = dst[e];
  int pos = atomicAdd(&fill[d], 1);
  srcS[pos] = src[e];
  wS[pos] = nrm[e];
}

// C[M,Nc] = A[M,K] @ B[K,Nc] (+bias)(relu).
// One 64-lane wave per block; 64x64 tile; 8x8 per thread; BK=8; dbuf LDS.
// Requires K % 8 == 0, Nc % 4 == 0.
template <bool BIAS, bool RELU>
__global__ __launch_bounds__(64, 3) void gemm_wave_kernel(const float* __restrict__ A,
                                                          const float* __restrict__ B,
                                                          const float* __restrict__ bias,
                                                          float* __restrict__ C,
                                                          int M, int K, int Nc) {
  __shared__ float As[2][8][64];  // [buf][k][m]
  __shared__ float Bs[2][8][64];  // [buf][k][n]
  const int lane = threadIdx.x;
  const int ty = lane >> 3, tx = lane & 7;
  const int m0 = blockIdx.y * 64, n0 = blockIdx.x * 64;
  const int mA = m0 + lane;                 // A-staging: one row per lane
  const bool aok = mA < M;
  const int rB = lane >> 3;                 // B-staging: row 0..7
  const int cB = (lane & 7) * 8;            // 8 cols per lane
  const int KT = K >> 3;

  float acc[8][8];
#pragma unroll
  for (int i = 0; i < 8; ++i)
#pragma unroll
    for (int j = 0; j < 8; ++j) acc[i][j] = 0.f;

  float4 aV0, aV1, bV0, bV1;

  auto gload = [&](int k0) {
    aV0 = aV1 = bV0 = bV1 = make_float4(0.f, 0.f, 0.f, 0.f);
    if (aok) {
      const float* ap = A + (size_t)mA * K + k0;
      aV0 = *reinterpret_cast<const float4*>(ap);
      aV1 = *reinterpret_cast<const float4*>(ap + 4);
    }
    const float* bp = B + (size_t)(k0 + rB) * Nc + n0 + cB;
    if (n0 + cB < Nc) bV0 = *reinterpret_cast<const float4*>(bp);       // Nc%4==0
    if (n0 + cB + 4 < Nc) bV1 = *reinterpret_cast<const float4*>(bp + 4);
  };

  auto sstore = [&](int buf) {
    As[buf][0][lane] = aV0.x;  // 2-way bank alias (free)
    As[buf][1][lane] = aV0.y;
    As[buf][2][lane] = aV0.z;
    As[buf][3][lane] = aV0.w;
    As[buf][4][lane] = aV1.x;
    As[buf][5][lane] = aV1.y;
    As[buf][6][lane] = aV1.z;
    As[buf][7][lane] = aV1.w;
    *reinterpret_cast<float4*>(&Bs[buf][rB][cB]) = bV0;
    *reinterpret_cast<float4*>(&Bs[buf][rB][cB + 4]) = bV1;
  };

  auto comp = [&](int buf) {
#pragma unroll
    for (int kk = 0; kk < 8; ++kk) {
      float4 a0 = *reinterpret_cast<const float4*>(&As[buf][kk][ty * 8]);
      float4 a1 = *reinterpret_cast<const float4*>(&As[buf][kk][ty * 8 + 4]);
      float4 b0 = *reinterpret_cast<const float4*>(&Bs[buf][kk][tx * 8]);
      float4 b1 = *reinterpret_cast<const float4*>(&Bs[buf][kk][tx * 8 + 4]);
      const float av[8] = {a0.x, a0.y, a0.z, a0.w, a1.x, a1.y, a1.z, a1.w};
      const float bv[8] = {b0.x, b0.y, b0.z, b0.w, b1.x, b1.y, b1.z, b1.w};
#pragma unroll
      for (int i = 0; i < 8; ++i)
#pragma unroll
        for (int j = 0; j < 8; ++j) acc[i][j] = fmaf(av[i], bv[j], acc[i][j]);
    }
  };

  gload(0);
  sstore(0);
  __syncthreads();  // 1-wave barrier: cheap
  for (int kt = 0; kt < KT; ++kt) {
    const bool more = (kt + 1 < KT);
    if (more) gload((kt + 1) * 8);  // prefetch to regs, in flight under compute
    comp(kt & 1);
    __syncthreads();
    if (more) {
      sstore((kt + 1) & 1);
      __syncthreads();
    }
  }

  // epilogue: 8 rows x 8 cols per thread
  const int nc0 = n0 + tx * 8;
  float4 bb0 = make_float4(0.f, 0.f, 0.f, 0.f), bb1 = bb0;
  if (BIAS) {
    if (nc0 < Nc) bb0 = *reinterpret_cast<const float4*>(bias + nc0);
    if (nc0 + 4 < Nc) bb1 = *reinterpret_cast<const float4*>(bias + nc0 + 4);
  }
#pragma unroll
  for (int i = 0; i < 8; ++i) {
    const int m = m0 + ty * 8 + i;
    if (m >= M) continue;
    float* cp = C + (size_t)m * Nc + nc0;
    if (nc0 < Nc) {
      float4 v = make_float4(acc[i][0], acc[i][1], acc[i][2], acc[i][3]);
      if (BIAS) { v.x += bb0.x; v.y += bb0.y; v.z += bb0.z; v.w += bb0.w; }
      if (RELU) {
        v.x = fmaxf(v.x, 0.f); v.y = fmaxf(v.y, 0.f);
        v.z = fmaxf(v.z, 0.f); v.w = fmaxf(v.w, 0.f);
      }
      *reinterpret_cast<float4*>(cp) = v;
    }
    if (nc0 + 4 < Nc) {
      float4 v = make_float4(acc[i][4], acc[i][5], acc[i][6], acc[i][7]);
      if (BIAS) { v.x += bb1.x; v.y += bb1.y; v.z += bb1.z; v.w += bb1.w; }
      if (RELU) {
        v.x = fmaxf(v.x, 0.f); v.y = fmaxf(v.y, 0.f);
        v.z = fmaxf(v.z, 0.f); v.w = fmaxf(v.w, 0.f);
      }
      *reinterpret_cast<float4*>(cp + 4) = v;
    }
  }
}

// Fused gather-aggregate + self-loop + bias + relu. One 64-lane wave per node.
template <int F>
__global__ __launch_bounds__(256) void agg_gather_kernel(const int* __restrict__ rowptr,
                                                         const int* __restrict__ srcS,
                                                         const float* __restrict__ wS,
                                                         const float* __restrict__ t,
                                                         const float* __restrict__ dinv,
                                                         const float* __restrict__ bias,
                                                         float* __restrict__ out) {
  constexpr int NITER = (F + 63) / 64;
  const int wv = threadIdx.x >> 6, lane = threadIdx.x & 63;
  const int node = blockIdx.x * 4 + wv;
  if (node >= NN) return;
  const int beg = rowptr[node], end = rowptr[node + 1];
  float acc[NITER];
#pragma unroll
  for (int i = 0; i < NITER; ++i) acc[i] = 0.f;
  for (int j = beg; j < end; ++j) {
    const int s = srcS[j];
    const float wgt = wS[j];
    const float* row = t + (size_t)s * F;
#pragma unroll
    for (int i = 0; i < NITER; ++i) {
      int f = lane + i * 64;
      if (f < F) acc[i] += row[f] * wgt;
    }
  }
  const float di = dinv[node];
  const float self_w = di * di;
  const float* trow = t + (size_t)node * F;
  float* orow = out + (size_t)node * F;
#pragma unroll
  for (int i = 0; i < NITER; ++i) {
    int f = lane + i * 64;
    if (f < F) {
      float v = fmaf(trow[f], self_w, acc[i]) + bias[f];
      orow[f] = fmaxf(v, 0.f);
    }
  }
}

extern "C" void kernel_launch(void* const* d_in, const int* in_sizes, int n_in,
                              void* d_out, int out_size, void* d_ws, size_t ws_size,
                              hipStream_t stream) {
  const float* x = (const float*)d_in[0];
  const int* ei = (const int*)d_in[1];  // int32 per harness conversion
  const float* ea = (const float*)d_in[2];
  const float* fcW = (const float*)d_in[3];
  const float* fcb = (const float*)d_in[4];
  const float* W1 = (const float*)d_in[5];
  const float* b1 = (const float*)d_in[6];
  const float* W2 = (const float*)d_in[7];
  const float* b2 = (const float*)d_in[8];
  const int* srcIdx = ei;       // edge_index[0]
  const int* dstIdx = ei + NE;  // edge_index[1]

  char* ws = (char*)d_ws;
  constexpr size_t MB = 1u << 20;
  float* dinv = (float*)(ws);            // 80 KB
  float* nrm = (float*)(ws + 1 * MB);    // 1.28 MB
  int* rowptr = (int*)(ws + 3 * MB);     // 80 KB (NN+1)
  int* cnt = (int*)(ws + 4 * MB);        // 80 KB (count, then fill cursor)
  int* srcS = (int*)(ws + 5 * MB);       // 1.28 MB
  float* wS = (float*)(ws + 7 * MB);     // 1.28 MB
  float* bufA = (float*)(ws + 9 * MB);   // 32 MB: h1 [N,400] -> h2 [N,200]
  float* bufB = (float*)(ws + 41 * MB);  // 16 MB: t1 [N,200] -> t2 [N,128]
  // peak ws use: 57 MB

  // --- normalization + CSR (shared by both GCN layers) ---
  hipMemsetAsync(dinv, 0, NN * sizeof(float), stream);
  hipMemsetAsync(cnt, 0, NN * sizeof(int), stream);
  deg_count_kernel<<<(NE + NN + 255) / 256, 256, 0, stream>>>(dstIdx, ea, dinv, cnt);
  dinv_kernel<<<(NN + 255) / 256, 256, 0, stream>>>(dinv);
  norm_kernel<<<(NE + 255) / 256, 256, 0, stream>>>(srcIdx, dstIdx, ea, dinv, nrm);
  scan_kernel<<<1, 1024, 0, stream>>>(cnt, rowptr);
  hipMemcpyAsync(cnt, rowptr, NN * sizeof(int), hipMemcpyDeviceToDevice, stream);
  scatter_kernel<<<(NE + 255) / 256, 256, 0, stream>>>(srcIdx, dstIdx, nrm, cnt, srcS, wS);

  const int MB64 = (NN + 63) / 64;  // 313 row blocks

  // --- h1 = relu(x @ fcW + fcb) ---
  float* h1 = bufA;
  gemm_wave_kernel<true, true><<<dim3((HID1 + 63) / 64, MB64), 64, 0, stream>>>(
      x, fcW, fcb, h1, NN, IN_FT, HID1);

  // --- layer 1: t1 = h1 @ W1; h2 = relu(agg(t1) + t1*dinv^2 + b1) ---
  float* t1 = bufB;
  gemm_wave_kernel<false, false><<<dim3((HID2 + 63) / 64, MB64), 64, 0, stream>>>(
      h1, W1, nullptr, t1, NN, HID1, HID2);
  float* h2 = bufA;  // h1 dead after t1 GEMM
  agg_gather_kernel<HID2><<<(NN + 3) / 4, 256, 0, stream>>>(
      rowptr, srcS, wS, t1, dinv, b1, h2);

  // --- layer 2: t2 = h2 @ W2; out = relu(agg(t2) + t2*dinv^2 + b2) ---
  float* t2 = bufB;  // t1 dead after agg1
  gemm_wave_kernel<false, false><<<dim3((OUT_FT + 63) / 64, MB64), 64, 0, stream>>>(
      h2, W2, nullptr, t2, NN, HID2, OUT_FT);
  agg_gather_kernel<OUT_FT><<<(NN + 3) / 4, 256, 0, stream>>>(
      rowptr, srcS, wS, t2, dinv, b2, (float*)d_out);
}

// Round 7
// 362.121 us; speedup vs baseline: 4.9312x; 2.7525x over previous
//
#include <hip/hip_runtime.h>

// GCN encoder: h1 = relu(x@fcW+fcb); h2 = relu(gcn(h1,W1,b1)); out = relu(gcn(h2,W2,b2))
// gcn(x,W,b)[i] = sum_{e:dst=i} (x@W)[src_e]*norm_e + (x@W)[i]*dinv[i]^2 + b
// Aggregation: dst-sorted CSR built on device, per-node gather (no fp32 atomics).
// GEMM: 128 threads (2 waves), 64x64 tile, 4x8/thread, BK=16.
// NOTE: no min-waves arg in __launch_bounds__ -- rounds 5/6 showed hipcc
// meets an occupancy floor by spilling the accumulator to scratch (1.8-3 GB
// of scratch traffic per GEMM). Unhinted kernels (rounds 3/4) never spilled.

namespace {
constexpr int NN = 20000;
constexpr int NE = 320000;
constexpr int IN_FT = 256, HID1 = 400, HID2 = 200, OUT_FT = 128;
}

// deg (weighted, +1 self loop) and integer count per dst in one pass
__global__ __launch_bounds__(256) void deg_count_kernel(const int* __restrict__ dst,
                                                        const float* __restrict__ ew,
                                                        float* __restrict__ deg,
                                                        int* __restrict__ cnt) {
  int tid = blockIdx.x * 256 + threadIdx.x;
  if (tid < NE) {
    int d = dst[tid];
    unsafeAtomicAdd(&deg[d], ew[tid]);
    atomicAdd(&cnt[d], 1);
  } else if (tid < NE + NN) {
    unsafeAtomicAdd(&deg[tid - NE], 1.0f);  // self-loop weight 1
  }
}

__global__ __launch_bounds__(256) void dinv_kernel(float* __restrict__ deg) {
  int i = blockIdx.x * 256 + threadIdx.x;
  if (i < NN) {
    float d = deg[i];
    deg[i] = d > 0.f ? rsqrtf(d) : 0.f;  // in place: deg -> dinv
  }
}

// single-block exclusive scan of count[NN] -> rowptr[NN+1]
__global__ __launch_bounds__(1024) void scan_kernel(const int* __restrict__ count,
                                                    int* __restrict__ rowptr) {
  constexpr int CHUNK = (NN + 1023) / 1024;  // 20
  __shared__ int partial[1024];
  const int t = threadIdx.x;
  const int base = t * CHUNK;
  int s = 0;
#pragma unroll
  for (int i = 0; i < CHUNK; ++i) {
    int idx = base + i;
    if (idx < NN) s += count[idx];
  }
  partial[t] = s;
  __syncthreads();
  for (int off = 1; off < 1024; off <<= 1) {
    int v = 0;
    if (t >= off) v = partial[t - off];
    __syncthreads();
    if (t >= off) partial[t] += v;
    __syncthreads();
  }
  int excl = partial[t] - s;
#pragma unroll
  for (int i = 0; i < CHUNK; ++i) {
    int idx = base + i;
    if (idx < NN) {
      rowptr[idx] = excl;
      excl += count[idx];
    }
  }
  if (t == 1023) rowptr[NN] = partial[1023];
}

// scatter edges into dst-sorted order, computing norm inline
__global__ __launch_bounds__(256) void scatter_kernel(const int* __restrict__ src,
                                                      const int* __restrict__ dst,
                                                      const float* __restrict__ ew,
                                                      const float* __restrict__ dinv,
                                                      int* __restrict__ fill,
                                                      int* __restrict__ srcS,
                                                      float* __restrict__ wS) {
  int e = blockIdx.x * 256 + threadIdx.x;
  if (e >= NE) return;
  int s = src[e], d = dst[e];
  int pos = atomicAdd(&fill[d], 1);
  srcS[pos] = s;
  wS[pos] = dinv[s] * ew[e] * dinv[d];
}

// C[M,Nc] = A[M,K] @ B[K,Nc] (+bias)(relu).
// 128 threads (2 waves); 64x64 tile; 4x8 per thread; BK=16 (zero-padded tail).
// Requires K % 4 == 0, Nc % 8 == 0.
template <bool BIAS, bool RELU>
__global__ __launch_bounds__(128) void gemm128_kernel(const float* __restrict__ A,
                                                      const float* __restrict__ B,
                                                      const float* __restrict__ bias,
                                                      float* __restrict__ C,
                                                      int M, int K, int Nc) {
  __shared__ float As[16][64];  // [k][m]
  __shared__ float Bs[16][64];  // [k][n]
  const int tid = threadIdx.x;
  const int tx = tid & 7;    // col group: 8 cols
  const int ty = tid >> 3;   // row group: 4 rows
  const int m0 = blockIdx.y * 64, n0 = blockIdx.x * 64;
  // A staging: thread -> row (tid&63), k-offset (tid>>6)*8; two float4
  const int ar = tid & 63;
  const int aq = (tid >> 6) * 8;
  const int am = m0 + ar;
  // B staging: thread -> k-row (tid>>3), col (tid&7)*8; two float4
  const int br = tid >> 3;
  const int bc = (tid & 7) * 8;
  const bool bcok = (n0 + bc) < Nc;  // Nc%8==0 -> whole 8-col chunk in/out

  float acc[4][8];
#pragma unroll
  for (int i = 0; i < 4; ++i)
#pragma unroll
    for (int j = 0; j < 8; ++j) acc[i][j] = 0.f;

  for (int k0 = 0; k0 < K; k0 += 16) {
    // stage A (zero-pad k tail)
    float4 a0 = make_float4(0.f, 0.f, 0.f, 0.f), a1 = a0;
    if (am < M) {
      const float* ap = A + (size_t)am * K + k0 + aq;
      if (k0 + aq < K) a0 = *reinterpret_cast<const float4*>(ap);       // K%4==0
      if (k0 + aq + 4 < K) a1 = *reinterpret_cast<const float4*>(ap + 4);
    }
    As[aq + 0][ar] = a0.x;
    As[aq + 1][ar] = a0.y;
    As[aq + 2][ar] = a0.z;
    As[aq + 3][ar] = a0.w;
    As[aq + 4][ar] = a1.x;
    As[aq + 5][ar] = a1.y;
    As[aq + 6][ar] = a1.z;
    As[aq + 7][ar] = a1.w;
    // stage B (zero-pad k tail, mask col overhang)
    float4 b0 = make_float4(0.f, 0.f, 0.f, 0.f), b1 = b0;
    if (bcok && (k0 + br) < K) {
      const float* bp = B + (size_t)(k0 + br) * Nc + n0 + bc;
      b0 = *reinterpret_cast<const float4*>(bp);
      b1 = *reinterpret_cast<const float4*>(bp + 4);
    }
    *reinterpret_cast<float4*>(&Bs[br][bc]) = b0;
    *reinterpret_cast<float4*>(&Bs[br][bc + 4]) = b1;
    __syncthreads();
#pragma unroll
    for (int kk = 0; kk < 16; ++kk) {
      float4 av = *reinterpret_cast<const float4*>(&As[kk][ty * 4]);
      float4 bv0 = *reinterpret_cast<const float4*>(&Bs[kk][tx * 8]);
      float4 bv1 = *reinterpret_cast<const float4*>(&Bs[kk][tx * 8 + 4]);
      const float a[4] = {av.x, av.y, av.z, av.w};
      const float b[8] = {bv0.x, bv0.y, bv0.z, bv0.w, bv1.x, bv1.y, bv1.z, bv1.w};
#pragma unroll
      for (int i = 0; i < 4; ++i)
#pragma unroll
        for (int j = 0; j < 8; ++j) acc[i][j] = fmaf(a[i], b[j], acc[i][j]);
    }
    __syncthreads();
  }

  // epilogue: 4 rows x 8 cols per thread
  const int nc0 = n0 + tx * 8;
  if (nc0 >= Nc) return;
  float4 bb0 = make_float4(0.f, 0.f, 0.f, 0.f), bb1 = bb0;
  if (BIAS) {
    bb0 = *reinterpret_cast<const float4*>(bias + nc0);
    bb1 = *reinterpret_cast<const float4*>(bias + nc0 + 4);
  }
#pragma unroll
  for (int i = 0; i < 4; ++i) {
    const int m = m0 + ty * 4 + i;
    if (m >= M) continue;
    float* cp = C + (size_t)m * Nc + nc0;
    float4 v0 = make_float4(acc[i][0], acc[i][1], acc[i][2], acc[i][3]);
    float4 v1 = make_float4(acc[i][4], acc[i][5], acc[i][6], acc[i][7]);
    if (BIAS) {
      v0.x += bb0.x; v0.y += bb0.y; v0.z += bb0.z; v0.w += bb0.w;
      v1.x += bb1.x; v1.y += bb1.y; v1.z += bb1.z; v1.w += bb1.w;
    }
    if (RELU) {
      v0.x = fmaxf(v0.x, 0.f); v0.y = fmaxf(v0.y, 0.f);
      v0.z = fmaxf(v0.z, 0.f); v0.w = fmaxf(v0.w, 0.f);
      v1.x = fmaxf(v1.x, 0.f); v1.y = fmaxf(v1.y, 0.f);
      v1.z = fmaxf(v1.z, 0.f); v1.w = fmaxf(v1.w, 0.f);
    }
    *reinterpret_cast<float4*>(cp) = v0;
    *reinterpret_cast<float4*>(cp + 4) = v1;
  }
}

// Fused gather-aggregate + self-loop + bias + relu. One 64-lane wave per node.
template <int F>
__global__ __launch_bounds__(256) void agg_gather_kernel(const int* __restrict__ rowptr,
                                                         const int* __restrict__ srcS,
                                                         const float* __restrict__ wS,
                                                         const float* __restrict__ t,
                                                         const float* __restrict__ dinv,
                                                         const float* __restrict__ bias,
                                                         float* __restrict__ out) {
  constexpr int NITER = (F + 63) / 64;
  const int wv = threadIdx.x >> 6, lane = threadIdx.x & 63;
  const int node = blockIdx.x * 4 + wv;
  if (node >= NN) return;
  const int beg = rowptr[node], end = rowptr[node + 1];
  float acc[NITER];
#pragma unroll
  for (int i = 0; i < NITER; ++i) acc[i] = 0.f;
  for (int j = beg; j < end; ++j) {
    const int s = srcS[j];
    const float wgt = wS[j];
    const float* row = t + (size_t)s * F;
#pragma unroll
    for (int i = 0; i < NITER; ++i) {
      int f = lane + i * 64;
      if (f < F) acc[i] += row[f] * wgt;
    }
  }
  const float di = dinv[node];
  const float self_w = di * di;
  const float* trow = t + (size_t)node * F;
  float* orow = out + (size_t)node * F;
#pragma unroll
  for (int i = 0; i < NITER; ++i) {
    int f = lane + i * 64;
    if (f < F) {
      float v = fmaf(trow[f], self_w, acc[i]) + bias[f];
      orow[f] = fmaxf(v, 0.f);
    }
  }
}

extern "C" void kernel_launch(void* const* d_in, const int* in_sizes, int n_in,
                              void* d_out, int out_size, void* d_ws, size_t ws_size,
                              hipStream_t stream) {
  const float* x = (const float*)d_in[0];
  const int* ei = (const int*)d_in[1];  // int32 per harness conversion
  const float* ea = (const float*)d_in[2];
  const float* fcW = (const float*)d_in[3];
  const float* fcb = (const float*)d_in[4];
  const float* W1 = (const float*)d_in[5];
  const float* b1 = (const float*)d_in[6];
  const float* W2 = (const float*)d_in[7];
  const float* b2 = (const float*)d_in[8];
  const int* srcIdx = ei;       // edge_index[0]
  const int* dstIdx = ei + NE;  // edge_index[1]

  char* ws = (char*)d_ws;
  constexpr size_t MB = 1u << 20;
  float* dinv = (float*)(ws);            // 80 KB
  int* rowptr = (int*)(ws + 1 * MB);     // 80 KB (NN+1)
  int* cnt = (int*)(ws + 2 * MB);        // 80 KB (count, then fill cursor)
  int* srcS = (int*)(ws + 3 * MB);       // 1.28 MB
  float* wS = (float*)(ws + 5 * MB);     // 1.28 MB
  float* bufA = (float*)(ws + 7 * MB);   // 32 MB: h1 [N,400] -> h2 [N,200]
  float* bufB = (float*)(ws + 39 * MB);  // 16 MB: t1 [N,200] -> t2 [N,128]
  // peak ws use: 55 MB

  // --- normalization + CSR (shared by both GCN layers) ---
  hipMemsetAsync(dinv, 0, NN * sizeof(float), stream);
  hipMemsetAsync(cnt, 0, NN * sizeof(int), stream);
  deg_count_kernel<<<(NE + NN + 255) / 256, 256, 0, stream>>>(dstIdx, ea, dinv, cnt);
  dinv_kernel<<<(NN + 255) / 256, 256, 0, stream>>>(dinv);
  scan_kernel<<<1, 1024, 0, stream>>>(cnt, rowptr);
  hipMemcpyAsync(cnt, rowptr, NN * sizeof(int), hipMemcpyDeviceToDevice, stream);
  scatter_kernel<<<(NE + 255) / 256, 256, 0, stream>>>(srcIdx, dstIdx, ea, dinv, cnt, srcS, wS);

  const int MB64 = (NN + 63) / 64;  // 313 row blocks

  // --- h1 = relu(x @ fcW + fcb) ---
  float* h1 = bufA;
  gemm128_kernel<true, true><<<dim3((HID1 + 63) / 64, MB64), 128, 0, stream>>>(
      x, fcW, fcb, h1, NN, IN_FT, HID1);

  // --- layer 1: t1 = h1 @ W1; h2 = relu(agg(t1) + t1*dinv^2 + b1) ---
  float* t1 = bufB;
  gemm128_kernel<false, false><<<dim3((HID2 + 63) / 64, MB64), 128, 0, stream>>>(
      h1, W1, nullptr, t1, NN, HID1, HID2);
  float* h2 = bufA;  // h1 dead after t1 GEMM
  agg_gather_kernel<HID2><<<(NN + 3) / 4, 256, 0, stream>>>(
      rowptr, srcS, wS, t1, dinv, b1, h2);

  // --- layer 2: t2 = h2 @ W2; out = relu(agg(t2) + t2*dinv^2 + b2) ---
  float* t2 = bufB;  // t1 dead after agg1
  gemm128_kernel<false, false><<<dim3((OUT_FT + 63) / 64, MB64), 128, 0, stream>>>(
      h2, W2, nullptr, t2, NN, HID2, OUT_FT);
  agg_gather_kernel<OUT_FT><<<(NN + 3) / 4, 256, 0, stream>>>(
      rowptr, srcS, wS, t2, dinv, b2, (float*)d_out);
}

// Round 8
// 311.824 us; speedup vs baseline: 5.7266x; 1.1613x over previous
//
#include <hip/hip_runtime.h>

// GCN encoder: h1 = relu(x@fcW+fcb); h2 = relu(gcn(h1,W1,b1)); out = relu(gcn(h2,W2,b2))
// gcn(x,W,b)[i] = sum_{e:dst=i} (x@W)[src_e]*norm_e + (x@W)[i]*dinv[i]^2 + b
// Aggregation: dst-sorted CSR built on device, per-node gather (no fp32 atomics).
// GEMM: split-bf16 MFMA. fp32 operands are decomposed during LDS staging into
// hi=bf16(v), lo=bf16(v-hi); C = Ahi*Bhi + Ahi*Blo + Alo*Bhi via
// v_mfma_f32_16x16x32_bf16 (error ~1e-4 rel, threshold 4.5e-3 abs).
// 128x64 tile, BK=32, 256 thr = 4 waves (2x2), wave = 4x2 16x16 frags.
// No min-waves in __launch_bounds__ (rounds 5/6: hipcc spills to meet it).

namespace {
constexpr int NN = 20000;
constexpr int NE = 320000;
constexpr int IN_FT = 256, HID1 = 400, HID2 = 200, OUT_FT = 128;
using short8v = __attribute__((ext_vector_type(8))) short;
using f32x4 = __attribute__((ext_vector_type(4))) float;
}

__device__ __forceinline__ unsigned short f2bf(float f) {
  unsigned int u = __float_as_uint(f);
  u += 0x7FFFu + ((u >> 16) & 1u);  // round-to-nearest-even
  return (unsigned short)(u >> 16);
}
__device__ __forceinline__ float bf2f(unsigned short h) {
  return __uint_as_float(((unsigned int)h) << 16);
}

// deg (weighted, +1 self loop) and integer count per dst in one pass
__global__ __launch_bounds__(256) void deg_count_kernel(const int* __restrict__ dst,
                                                        const float* __restrict__ ew,
                                                        float* __restrict__ deg,
                                                        int* __restrict__ cnt) {
  int tid = blockIdx.x * 256 + threadIdx.x;
  if (tid < NE) {
    int d = dst[tid];
    unsafeAtomicAdd(&deg[d], ew[tid]);
    atomicAdd(&cnt[d], 1);
  } else if (tid < NE + NN) {
    unsafeAtomicAdd(&deg[tid - NE], 1.0f);  // self-loop weight 1
  }
}

__global__ __launch_bounds__(256) void dinv_kernel(float* __restrict__ deg) {
  int i = blockIdx.x * 256 + threadIdx.x;
  if (i < NN) {
    float d = deg[i];
    deg[i] = d > 0.f ? rsqrtf(d) : 0.f;  // in place: deg -> dinv
  }
}

// single-block exclusive scan: count[NN] -> rowptr[NN+1], and fill cursor
// (cnt overwritten in place with the exclusive prefix for scatter).
__global__ __launch_bounds__(1024) void scan_kernel(int* __restrict__ count,
                                                    int* __restrict__ rowptr) {
  constexpr int CHUNK = (NN + 1023) / 1024;  // 20
  __shared__ int partial[1024];
  const int t = threadIdx.x;
  const int base = t * CHUNK;
  int s = 0;
#pragma unroll
  for (int i = 0; i < CHUNK; ++i) {
    int idx = base + i;
    if (idx < NN) s += count[idx];
  }
  partial[t] = s;
  __syncthreads();
  for (int off = 1; off < 1024; off <<= 1) {
    int v = 0;
    if (t >= off) v = partial[t - off];
    __syncthreads();
    if (t >= off) partial[t] += v;
    __syncthreads();
  }
  int excl = partial[t] - s;
#pragma unroll
  for (int i = 0; i < CHUNK; ++i) {
    int idx = base + i;
    if (idx < NN) {
      int c = count[idx];
      rowptr[idx] = excl;
      count[idx] = excl;  // becomes the scatter fill cursor
      excl += c;
    }
  }
  if (t == 1023) rowptr[NN] = partial[1023];
}

// scatter edges into dst-sorted order, computing norm inline
__global__ __launch_bounds__(256) void scatter_kernel(const int* __restrict__ src,
                                                      const int* __restrict__ dst,
                                                      const float* __restrict__ ew,
                                                      const float* __restrict__ dinv,
                                                      int* __restrict__ fill,
                                                      int* __restrict__ srcS,
                                                      float* __restrict__ wS) {
  int e = blockIdx.x * 256 + threadIdx.x;
  if (e >= NE) return;
  int s = src[e], d = dst[e];
  int pos = atomicAdd(&fill[d], 1);
  srcS[pos] = s;
  wS[pos] = dinv[s] * ew[e] * dinv[d];
}

// C[M,N] = A[M,K] @ B[K,N] (+bias)(relu) via split-bf16 MFMA.
// Requires K % 4 == 0, N % 8 == 0.
template <bool BIAS, bool RELU>
__global__ __launch_bounds__(256) void gemm_mfma_kernel(const float* __restrict__ A,
                                                        const float* __restrict__ B,
                                                        const float* __restrict__ bias,
                                                        float* __restrict__ C,
                                                        int M, int K, int N) {
  // padded row stride 40 elems (80 B) -> conflict-light b128 frag reads
  __shared__ unsigned short Ash[128][40];
  __shared__ unsigned short Asl[128][40];
  __shared__ unsigned short Bsh[64][40];
  __shared__ unsigned short Bsl[64][40];
  const int tid = threadIdx.x;
  const int lane = tid & 63;
  const int wid = tid >> 6;
  const int wm = wid >> 1, wn = wid & 1;  // 2x2 wave grid
  const int m0 = blockIdx.y * 128, n0 = blockIdx.x * 64;
  const int ar = tid >> 1, ako = (tid & 1) * 16;  // A staging: row, k-offset
  const int arow = m0 + ar;
  const int bk = tid >> 3, bnc = (tid & 7) * 8;   // B staging: k-row, col-offset
  const int l15 = lane & 15, kg = lane >> 4;

  f32x4 acc[4][2];
#pragma unroll
  for (int i = 0; i < 4; ++i)
#pragma unroll
    for (int j = 0; j < 2; ++j)
#pragma unroll
      for (int c = 0; c < 4; ++c) acc[i][j][c] = 0.f;

  for (int k0 = 0; k0 < K; k0 += 32) {
    {  // stage A: 16 f32 per thread -> hi/lo bf16 (zero-pad K tail)
      const float* ap = A + (size_t)arow * K + k0 + ako;
      float v[16];
#pragma unroll
      for (int q = 0; q < 4; ++q) {
        float4 t = make_float4(0.f, 0.f, 0.f, 0.f);
        if (arow < M && (k0 + ako + q * 4) < K)  // K%4==0: whole float4 valid
          t = *reinterpret_cast<const float4*>(ap + q * 4);
        v[q * 4 + 0] = t.x; v[q * 4 + 1] = t.y; v[q * 4 + 2] = t.z; v[q * 4 + 3] = t.w;
      }
      short8v h0, h1, l0, l1;
#pragma unroll
      for (int j = 0; j < 8; ++j) {
        unsigned short h = f2bf(v[j]);
        h0[j] = (short)h;
        l0[j] = (short)f2bf(v[j] - bf2f(h));
      }
#pragma unroll
      for (int j = 0; j < 8; ++j) {
        unsigned short h = f2bf(v[8 + j]);
        h1[j] = (short)h;
        l1[j] = (short)f2bf(v[8 + j] - bf2f(h));
      }
      *reinterpret_cast<short8v*>(&Ash[ar][ako]) = h0;
      *reinterpret_cast<short8v*>(&Ash[ar][ako + 8]) = h1;
      *reinterpret_cast<short8v*>(&Asl[ar][ako]) = l0;
      *reinterpret_cast<short8v*>(&Asl[ar][ako + 8]) = l1;
    }
    {  // stage B: one k-row x 8 cols -> transposed LDS [n][k]
      const int krow = k0 + bk;
      float4 t0 = make_float4(0.f, 0.f, 0.f, 0.f), t1 = t0;
      if (krow < K && (n0 + bnc) < N) {  // N%8==0: whole 8-col chunk valid
        const float* bp = B + (size_t)krow * N + n0 + bnc;
        t0 = *reinterpret_cast<const float4*>(bp);
        t1 = *reinterpret_cast<const float4*>(bp + 4);
      }
      float w[8] = {t0.x, t0.y, t0.z, t0.w, t1.x, t1.y, t1.z, t1.w};
#pragma unroll
      for (int j = 0; j < 8; ++j) {
        unsigned short h = f2bf(w[j]);
        Bsh[bnc + j][bk] = h;
        Bsl[bnc + j][bk] = f2bf(w[j] - bf2f(h));
      }
    }
    __syncthreads();
    // fragment reads: lane l15 = row (A) / col (B), kg selects 8-k slice
    short8v afh[4], afl[4], bfh[2], bfl[2];
#pragma unroll
    for (int mf = 0; mf < 4; ++mf) {
      const int r = wm * 64 + mf * 16 + l15;
      afh[mf] = *reinterpret_cast<const short8v*>(&Ash[r][kg * 8]);
      afl[mf] = *reinterpret_cast<const short8v*>(&Asl[r][kg * 8]);
    }
#pragma unroll
    for (int nf = 0; nf < 2; ++nf) {
      const int c = wn * 32 + nf * 16 + l15;
      bfh[nf] = *reinterpret_cast<const short8v*>(&Bsh[c][kg * 8]);
      bfl[nf] = *reinterpret_cast<const short8v*>(&Bsl[c][kg * 8]);
    }
#pragma unroll
    for (int mf = 0; mf < 4; ++mf)
#pragma unroll
      for (int nf = 0; nf < 2; ++nf) {
        acc[mf][nf] = __builtin_amdgcn_mfma_f32_16x16x32_bf16(afh[mf], bfh[nf], acc[mf][nf], 0, 0, 0);
        acc[mf][nf] = __builtin_amdgcn_mfma_f32_16x16x32_bf16(afh[mf], bfl[nf], acc[mf][nf], 0, 0, 0);
        acc[mf][nf] = __builtin_amdgcn_mfma_f32_16x16x32_bf16(afl[mf], bfh[nf], acc[mf][nf], 0, 0, 0);
      }
    __syncthreads();
  }

  // epilogue: C/D layout col=lane&15, row=(lane>>4)*4+reg (guide §3, m89/m91)
#pragma unroll
  for (int nf = 0; nf < 2; ++nf) {
    const int col = n0 + wn * 32 + nf * 16 + l15;
    if (col >= N) continue;
    float bb = 0.f;
    if (BIAS) bb = bias[col];
#pragma unroll
    for (int mf = 0; mf < 4; ++mf) {
      const int rbase = m0 + wm * 64 + mf * 16 + kg * 4;
#pragma unroll
      for (int i = 0; i < 4; ++i) {
        const int row = rbase + i;
        if (row >= M) continue;
        float v = acc[mf][nf][i];
        if (BIAS) v += bb;
        if (RELU) v = fmaxf(v, 0.f);
        C[(size_t)row * N + col] = v;
      }
    }
  }
}

// Fused gather-aggregate + self-loop + bias + relu. One 64-lane wave per node.
template <int F>
__global__ __launch_bounds__(256) void agg_gather_kernel(const int* __restrict__ rowptr,
                                                         const int* __restrict__ srcS,
                                                         const float* __restrict__ wS,
                                                         const float* __restrict__ t,
                                                         const float* __restrict__ dinv,
                                                         const float* __restrict__ bias,
                                                         float* __restrict__ out) {
  constexpr int NITER = (F + 63) / 64;
  const int wv = threadIdx.x >> 6, lane = threadIdx.x & 63;
  const int node = blockIdx.x * 4 + wv;
  if (node >= NN) return;
  const int beg = rowptr[node], end = rowptr[node + 1];
  float acc[NITER];
#pragma unroll
  for (int i = 0; i < NITER; ++i) acc[i] = 0.f;
  for (int j = beg; j < end; ++j) {
    const int s = srcS[j];
    const float wgt = wS[j];
    const float* row = t + (size_t)s * F;
#pragma unroll
    for (int i = 0; i < NITER; ++i) {
      int f = lane + i * 64;
      if (f < F) acc[i] += row[f] * wgt;
    }
  }
  const float di = dinv[node];
  const float self_w = di * di;
  const float* trow = t + (size_t)node * F;
  float* orow = out + (size_t)node * F;
#pragma unroll
  for (int i = 0; i < NITER; ++i) {
    int f = lane + i * 64;
    if (f < F) {
      float v = fmaf(trow[f], self_w, acc[i]) + bias[f];
      orow[f] = fmaxf(v, 0.f);
    }
  }
}

extern "C" void kernel_launch(void* const* d_in, const int* in_sizes, int n_in,
                              void* d_out, int out_size, void* d_ws, size_t ws_size,
                              hipStream_t stream) {
  const float* x = (const float*)d_in[0];
  const int* ei = (const int*)d_in[1];  // int32 per harness conversion
  const float* ea = (const float*)d_in[2];
  const float* fcW = (const float*)d_in[3];
  const float* fcb = (const float*)d_in[4];
  const float* W1 = (const float*)d_in[5];
  const float* b1 = (const float*)d_in[6];
  const float* W2 = (const float*)d_in[7];
  const float* b2 = (const float*)d_in[8];
  const int* srcIdx = ei;       // edge_index[0]
  const int* dstIdx = ei + NE;  // edge_index[1]

  char* ws = (char*)d_ws;
  constexpr size_t MB = 1u << 20;
  float* dinv = (float*)(ws);            // 80 KB
  int* rowptr = (int*)(ws + 1 * MB);     // 80 KB (NN+1)
  int* cnt = (int*)(ws + 2 * MB);        // 80 KB (count -> fill cursor)
  int* srcS = (int*)(ws + 3 * MB);       // 1.28 MB
  float* wS = (float*)(ws + 5 * MB);     // 1.28 MB
  float* bufA = (float*)(ws + 7 * MB);   // 32 MB: h1 [N,400] -> h2 [N,200]
  float* bufB = (float*)(ws + 39 * MB);  // 16 MB: t1 [N,200] -> t2 [N,128]
  // peak ws use: 55 MB

  // --- normalization + CSR (shared by both GCN layers) ---
  hipMemsetAsync(dinv, 0, NN * sizeof(float), stream);
  hipMemsetAsync(cnt, 0, NN * sizeof(int), stream);
  deg_count_kernel<<<(NE + NN + 255) / 256, 256, 0, stream>>>(dstIdx, ea, dinv, cnt);
  dinv_kernel<<<(NN + 255) / 256, 256, 0, stream>>>(dinv);
  scan_kernel<<<1, 1024, 0, stream>>>(cnt, rowptr);
  scatter_kernel<<<(NE + 255) / 256, 256, 0, stream>>>(srcIdx, dstIdx, ea, dinv, cnt, srcS, wS);

  const int MBLK = (NN + 127) / 128;  // 157 row blocks

  // --- h1 = relu(x @ fcW + fcb) ---
  float* h1 = bufA;
  gemm_mfma_kernel<true, true><<<dim3((HID1 + 63) / 64, MBLK), 256, 0, stream>>>(
      x, fcW, fcb, h1, NN, IN_FT, HID1);

  // --- layer 1: t1 = h1 @ W1; h2 = relu(agg(t1) + t1*dinv^2 + b1) ---
  float* t1 = bufB;
  gemm_mfma_kernel<false, false><<<dim3((HID2 + 63) / 64, MBLK), 256, 0, stream>>>(
      h1, W1, nullptr, t1, NN, HID1, HID2);
  float* h2 = bufA;  // h1 dead after t1 GEMM
  agg_gather_kernel<HID2><<<(NN + 3) / 4, 256, 0, stream>>>(
      rowptr, srcS, wS, t1, dinv, b1, h2);

  // --- layer 2: t2 = h2 @ W2; out = relu(agg(t2) + t2*dinv^2 + b2) ---
  float* t2 = bufB;  // t1 dead after agg1
  gemm_mfma_kernel<false, false><<<dim3((OUT_FT + 63) / 64, MBLK), 256, 0, stream>>>(
      h2, W2, nullptr, t2, NN, HID2, OUT_FT);
  agg_gather_kernel<OUT_FT><<<(NN + 3) / 4, 256, 0, stream>>>(
      rowptr, srcS, wS, t2, dinv, b2, (float*)d_out);
}

// Round 9
// 280.008 us; speedup vs baseline: 6.3773x; 1.1136x over previous
//
#include <hip/hip_runtime.h>

// GCN encoder: h1 = relu(x@fcW+fcb); h2 = relu(gcn(h1,W1,b1)); out = relu(gcn(h2,W2,b2))
// gcn(x,W,b)[i] = sum_{e:dst=i} (x@W)[src_e]*norm_e + (x@W)[i]*dinv[i]^2 + b
// Aggregation: dst-sorted CSR built on device; per-node float4 gather
// (1 dwordx4 load per edge per lane; 2 nodes/wave when F<=128).
// GEMM: split-bf16 MFMA (hi/lo decomposition, 3 mfma passes), 128x64 tile.
// No min-waves in __launch_bounds__ (rounds 5/6: hipcc spills to meet it).

namespace {
constexpr int NN = 20000;
constexpr int NE = 320000;
constexpr int IN_FT = 256, HID1 = 400, HID2 = 200, OUT_FT = 128;
using short8v = __attribute__((ext_vector_type(8))) short;
using f32x4 = __attribute__((ext_vector_type(4))) float;
}

__device__ __forceinline__ unsigned short f2bf(float f) {
  unsigned int u = __float_as_uint(f);
  u += 0x7FFFu + ((u >> 16) & 1u);  // round-to-nearest-even
  return (unsigned short)(u >> 16);
}
__device__ __forceinline__ float bf2f(unsigned short h) {
  return __uint_as_float(((unsigned int)h) << 16);
}

// deg (weighted, +1 self loop) and integer count per dst in one pass
__global__ __launch_bounds__(256) void deg_count_kernel(const int* __restrict__ dst,
                                                        const float* __restrict__ ew,
                                                        float* __restrict__ deg,
                                                        int* __restrict__ cnt) {
  int tid = blockIdx.x * 256 + threadIdx.x;
  if (tid < NE) {
    int d = dst[tid];
    unsafeAtomicAdd(&deg[d], ew[tid]);
    atomicAdd(&cnt[d], 1);
  } else if (tid < NE + NN) {
    unsafeAtomicAdd(&deg[tid - NE], 1.0f);  // self-loop weight 1
  }
}

__global__ __launch_bounds__(256) void dinv_kernel(float* __restrict__ deg) {
  int i = blockIdx.x * 256 + threadIdx.x;
  if (i < NN) {
    float d = deg[i];
    deg[i] = d > 0.f ? rsqrtf(d) : 0.f;  // in place: deg -> dinv
  }
}

// single-block exclusive scan: count[NN] -> rowptr[NN+1]; count becomes fill cursor
__global__ __launch_bounds__(1024) void scan_kernel(int* __restrict__ count,
                                                    int* __restrict__ rowptr) {
  constexpr int CHUNK = (NN + 1023) / 1024;  // 20
  __shared__ int partial[1024];
  const int t = threadIdx.x;
  const int base = t * CHUNK;
  int s = 0;
#pragma unroll
  for (int i = 0; i < CHUNK; ++i) {
    int idx = base + i;
    if (idx < NN) s += count[idx];
  }
  partial[t] = s;
  __syncthreads();
  for (int off = 1; off < 1024; off <<= 1) {
    int v = 0;
    if (t >= off) v = partial[t - off];
    __syncthreads();
    if (t >= off) partial[t] += v;
    __syncthreads();
  }
  int excl = partial[t] - s;
#pragma unroll
  for (int i = 0; i < CHUNK; ++i) {
    int idx = base + i;
    if (idx < NN) {
      int c = count[idx];
      rowptr[idx] = excl;
      count[idx] = excl;  // becomes the scatter fill cursor
      excl += c;
    }
  }
  if (t == 1023) rowptr[NN] = partial[1023];
}

// scatter edges into dst-sorted order, computing norm inline
__global__ __launch_bounds__(256) void scatter_kernel(const int* __restrict__ src,
                                                      const int* __restrict__ dst,
                                                      const float* __restrict__ ew,
                                                      const float* __restrict__ dinv,
                                                      int* __restrict__ fill,
                                                      int* __restrict__ srcS,
                                                      float* __restrict__ wS) {
  int e = blockIdx.x * 256 + threadIdx.x;
  if (e >= NE) return;
  int s = src[e], d = dst[e];
  int pos = atomicAdd(&fill[d], 1);
  srcS[pos] = s;
  wS[pos] = dinv[s] * ew[e] * dinv[d];
}

// C[M,N] = A[M,K] @ B[K,N] (+bias)(relu) via split-bf16 MFMA.
// Requires K % 4 == 0, N % 8 == 0.
template <bool BIAS, bool RELU>
__global__ __launch_bounds__(256) void gemm_mfma_kernel(const float* __restrict__ A,
                                                        const float* __restrict__ B,
                                                        const float* __restrict__ bias,
                                                        float* __restrict__ C,
                                                        int M, int K, int N) {
  __shared__ unsigned short Ash[128][40];
  __shared__ unsigned short Asl[128][40];
  __shared__ unsigned short Bsh[64][40];
  __shared__ unsigned short Bsl[64][40];
  const int tid = threadIdx.x;
  const int lane = tid & 63;
  const int wid = tid >> 6;
  const int wm = wid >> 1, wn = wid & 1;  // 2x2 wave grid
  const int m0 = blockIdx.y * 128, n0 = blockIdx.x * 64;
  const int ar = tid >> 1, ako = (tid & 1) * 16;  // A staging: row, k-offset
  const int arow = m0 + ar;
  const int bk = tid >> 3, bnc = (tid & 7) * 8;   // B staging: k-row, col-offset
  const int l15 = lane & 15, kg = lane >> 4;

  f32x4 acc[4][2];
#pragma unroll
  for (int i = 0; i < 4; ++i)
#pragma unroll
    for (int j = 0; j < 2; ++j)
#pragma unroll
      for (int c = 0; c < 4; ++c) acc[i][j][c] = 0.f;

  for (int k0 = 0; k0 < K; k0 += 32) {
    {  // stage A: 16 f32 per thread -> hi/lo bf16 (zero-pad K tail)
      const float* ap = A + (size_t)arow * K + k0 + ako;
      float v[16];
#pragma unroll
      for (int q = 0; q < 4; ++q) {
        float4 t = make_float4(0.f, 0.f, 0.f, 0.f);
        if (arow < M && (k0 + ako + q * 4) < K)  // K%4==0: whole float4 valid
          t = *reinterpret_cast<const float4*>(ap + q * 4);
        v[q * 4 + 0] = t.x; v[q * 4 + 1] = t.y; v[q * 4 + 2] = t.z; v[q * 4 + 3] = t.w;
      }
      short8v h0, h1, l0, l1;
#pragma unroll
      for (int j = 0; j < 8; ++j) {
        unsigned short h = f2bf(v[j]);
        h0[j] = (short)h;
        l0[j] = (short)f2bf(v[j] - bf2f(h));
      }
#pragma unroll
      for (int j = 0; j < 8; ++j) {
        unsigned short h = f2bf(v[8 + j]);
        h1[j] = (short)h;
        l1[j] = (short)f2bf(v[8 + j] - bf2f(h));
      }
      *reinterpret_cast<short8v*>(&Ash[ar][ako]) = h0;
      *reinterpret_cast<short8v*>(&Ash[ar][ako + 8]) = h1;
      *reinterpret_cast<short8v*>(&Asl[ar][ako]) = l0;
      *reinterpret_cast<short8v*>(&Asl[ar][ako + 8]) = l1;
    }
    {  // stage B: one k-row x 8 cols -> transposed LDS [n][k]
      const int krow = k0 + bk;
      float4 t0 = make_float4(0.f, 0.f, 0.f, 0.f), t1 = t0;
      if (krow < K && (n0 + bnc) < N) {  // N%8==0: whole 8-col chunk valid
        const float* bp = B + (size_t)krow * N + n0 + bnc;
        t0 = *reinterpret_cast<const float4*>(bp);
        t1 = *reinterpret_cast<const float4*>(bp + 4);
      }
      float w[8] = {t0.x, t0.y, t0.z, t0.w, t1.x, t1.y, t1.z, t1.w};
#pragma unroll
      for (int j = 0; j < 8; ++j) {
        unsigned short h = f2bf(w[j]);
        Bsh[bnc + j][bk] = h;
        Bsl[bnc + j][bk] = f2bf(w[j] - bf2f(h));
      }
    }
    __syncthreads();
    short8v afh[4], afl[4], bfh[2], bfl[2];
#pragma unroll
    for (int mf = 0; mf < 4; ++mf) {
      const int r = wm * 64 + mf * 16 + l15;
      afh[mf] = *reinterpret_cast<const short8v*>(&Ash[r][kg * 8]);
      afl[mf] = *reinterpret_cast<const short8v*>(&Asl[r][kg * 8]);
    }
#pragma unroll
    for (int nf = 0; nf < 2; ++nf) {
      const int c = wn * 32 + nf * 16 + l15;
      bfh[nf] = *reinterpret_cast<const short8v*>(&Bsh[c][kg * 8]);
      bfl[nf] = *reinterpret_cast<const short8v*>(&Bsl[c][kg * 8]);
    }
#pragma unroll
    for (int mf = 0; mf < 4; ++mf)
#pragma unroll
      for (int nf = 0; nf < 2; ++nf) {
        acc[mf][nf] = __builtin_amdgcn_mfma_f32_16x16x32_bf16(afh[mf], bfh[nf], acc[mf][nf], 0, 0, 0);
        acc[mf][nf] = __builtin_amdgcn_mfma_f32_16x16x32_bf16(afh[mf], bfl[nf], acc[mf][nf], 0, 0, 0);
        acc[mf][nf] = __builtin_amdgcn_mfma_f32_16x16x32_bf16(afl[mf], bfh[nf], acc[mf][nf], 0, 0, 0);
      }
    __syncthreads();
  }

  // epilogue: C/D layout col=lane&15, row=(lane>>4)*4+reg (guide §3, m89/m91)
#pragma unroll
  for (int nf = 0; nf < 2; ++nf) {
    const int col = n0 + wn * 32 + nf * 16 + l15;
    if (col >= N) continue;
    float bb = 0.f;
    if (BIAS) bb = bias[col];
#pragma unroll
    for (int mf = 0; mf < 4; ++mf) {
      const int rbase = m0 + wm * 64 + mf * 16 + kg * 4;
#pragma unroll
      for (int i = 0; i < 4; ++i) {
        const int row = rbase + i;
        if (row >= M) continue;
        float v = acc[mf][nf][i];
        if (BIAS) v += bb;
        if (RELU) v = fmaxf(v, 0.f);
        C[(size_t)row * N + col] = v;
      }
    }
  }
}

// Fused gather-aggregate + self-loop + bias + relu.
// NPW nodes per wave; each node served by F/4 lanes doing ONE float4 per edge.
// NPW=1: lanes 0..(F/4-1) active. NPW=2 (F<=128): half-wave per node.
template <int F, int NPW>
__global__ __launch_bounds__(256) void agg_gather_kernel(const int* __restrict__ rowptr,
                                                         const int* __restrict__ srcS,
                                                         const float* __restrict__ wS,
                                                         const float* __restrict__ t,
                                                         const float* __restrict__ dinv,
                                                         const float* __restrict__ bias,
                                                         float* __restrict__ out) {
  constexpr int LPN = F / 4;  // float4 lanes per node (F%4==0)
  const int wv = threadIdx.x >> 6;
  const int lane = threadIdx.x & 63;
  const int sub = (NPW == 2) ? (lane >> 5) : 0;
  const int l = (NPW == 2) ? (lane & 31) : lane;
  const int node = blockIdx.x * (4 * NPW) + wv * NPW + sub;
  if (node >= NN || l >= LPN) return;  // no barriers/shuffles below: safe exit
  const int beg = rowptr[node], end = rowptr[node + 1];
  const size_t fo = (size_t)l * 4;
  float4 acc0 = make_float4(0.f, 0.f, 0.f, 0.f);
  float4 acc1 = make_float4(0.f, 0.f, 0.f, 0.f);
  int j = beg;
  for (; j + 1 < end; j += 2) {  // 2-way unroll: two independent load->FMA chains
    const int s0 = srcS[j], s1 = srcS[j + 1];
    const float w0 = wS[j], w1 = wS[j + 1];
    const float4 v0 = *reinterpret_cast<const float4*>(t + (size_t)s0 * F + fo);
    const float4 v1 = *reinterpret_cast<const float4*>(t + (size_t)s1 * F + fo);
    acc0.x = fmaf(v0.x, w0, acc0.x); acc0.y = fmaf(v0.y, w0, acc0.y);
    acc0.z = fmaf(v0.z, w0, acc0.z); acc0.w = fmaf(v0.w, w0, acc0.w);
    acc1.x = fmaf(v1.x, w1, acc1.x); acc1.y = fmaf(v1.y, w1, acc1.y);
    acc1.z = fmaf(v1.z, w1, acc1.z); acc1.w = fmaf(v1.w, w1, acc1.w);
  }
  if (j < end) {
    const int s0 = srcS[j];
    const float w0 = wS[j];
    const float4 v0 = *reinterpret_cast<const float4*>(t + (size_t)s0 * F + fo);
    acc0.x = fmaf(v0.x, w0, acc0.x); acc0.y = fmaf(v0.y, w0, acc0.y);
    acc0.z = fmaf(v0.z, w0, acc0.z); acc0.w = fmaf(v0.w, w0, acc0.w);
  }
  const float di = dinv[node];
  const float sw = di * di;
  const float4 tv = *reinterpret_cast<const float4*>(t + (size_t)node * F + fo);
  const float4 bb = *reinterpret_cast<const float4*>(bias + fo);
  float4 o;
  o.x = fmaxf(fmaf(tv.x, sw, acc0.x + acc1.x) + bb.x, 0.f);
  o.y = fmaxf(fmaf(tv.y, sw, acc0.y + acc1.y) + bb.y, 0.f);
  o.z = fmaxf(fmaf(tv.z, sw, acc0.z + acc1.z) + bb.z, 0.f);
  o.w = fmaxf(fmaf(tv.w, sw, acc0.w + acc1.w) + bb.w, 0.f);
  *reinterpret_cast<float4*>(out + (size_t)node * F + fo) = o;
}

extern "C" void kernel_launch(void* const* d_in, const int* in_sizes, int n_in,
                              void* d_out, int out_size, void* d_ws, size_t ws_size,
                              hipStream_t stream) {
  const float* x = (const float*)d_in[0];
  const int* ei = (const int*)d_in[1];  // int32 per harness conversion
  const float* ea = (const float*)d_in[2];
  const float* fcW = (const float*)d_in[3];
  const float* fcb = (const float*)d_in[4];
  const float* W1 = (const float*)d_in[5];
  const float* b1 = (const float*)d_in[6];
  const float* W2 = (const float*)d_in[7];
  const float* b2 = (const float*)d_in[8];
  const int* srcIdx = ei;       // edge_index[0]
  const int* dstIdx = ei + NE;  // edge_index[1]

  char* ws = (char*)d_ws;
  constexpr size_t MB = 1u << 20;
  float* dinv = (float*)(ws);            // 80 KB
  int* rowptr = (int*)(ws + 1 * MB);     // 80 KB (NN+1)
  int* cnt = (int*)(ws + 2 * MB);        // 80 KB (count -> fill cursor)
  int* srcS = (int*)(ws + 3 * MB);       // 1.28 MB
  float* wS = (float*)(ws + 5 * MB);     // 1.28 MB
  float* bufA = (float*)(ws + 7 * MB);   // 32 MB: h1 [N,400] -> h2 [N,200]
  float* bufB = (float*)(ws + 39 * MB);  // 16 MB: t1 [N,200] -> t2 [N,128]
  // peak ws use: 55 MB

  // --- normalization + CSR (shared by both GCN layers) ---
  hipMemsetAsync(dinv, 0, NN * sizeof(float), stream);
  hipMemsetAsync(cnt, 0, NN * sizeof(int), stream);
  deg_count_kernel<<<(NE + NN + 255) / 256, 256, 0, stream>>>(dstIdx, ea, dinv, cnt);
  dinv_kernel<<<(NN + 255) / 256, 256, 0, stream>>>(dinv);
  scan_kernel<<<1, 1024, 0, stream>>>(cnt, rowptr);
  scatter_kernel<<<(NE + 255) / 256, 256, 0, stream>>>(srcIdx, dstIdx, ea, dinv, cnt, srcS, wS);

  const int MBLK = (NN + 127) / 128;  // 157 row blocks

  // --- h1 = relu(x @ fcW + fcb) ---
  float* h1 = bufA;
  gemm_mfma_kernel<true, true><<<dim3((HID1 + 63) / 64, MBLK), 256, 0, stream>>>(
      x, fcW, fcb, h1, NN, IN_FT, HID1);

  // --- layer 1: t1 = h1 @ W1; h2 = relu(agg(t1) + t1*dinv^2 + b1) ---
  float* t1 = bufB;
  gemm_mfma_kernel<false, false><<<dim3((HID2 + 63) / 64, MBLK), 256, 0, stream>>>(
      h1, W1, nullptr, t1, NN, HID1, HID2);
  float* h2 = bufA;  // h1 dead after t1 GEMM
  agg_gather_kernel<HID2, 1><<<(NN + 3) / 4, 256, 0, stream>>>(
      rowptr, srcS, wS, t1, dinv, b1, h2);

  // --- layer 2: t2 = h2 @ W2; out = relu(agg(t2) + t2*dinv^2 + b2) ---
  float* t2 = bufB;  // t1 dead after agg1
  gemm_mfma_kernel<false, false><<<dim3((OUT_FT + 63) / 64, MBLK), 256, 0, stream>>>(
      h2, W2, nullptr, t2, NN, HID2, OUT_FT);
  agg_gather_kernel<OUT_FT, 2><<<(NN + 7) / 8, 256, 0, stream>>>(
      rowptr, srcS, wS, t2, dinv, b2, (float*)d_out);
}